// Round 2
// baseline (2375.912 us; speedup 1.0000x reference)
//
#include <hip/hip_runtime.h>
#include <math.h>

#define NTOK   4096   // BATCH * L
#define LSEQ   2048
#define DMODEL 2048
#define DINNER 4096
#define NSTATE 16

using short8 = __attribute__((ext_vector_type(8))) short;
using f32x4  = __attribute__((ext_vector_type(4))) float;

__device__ inline float b2f(short s) {
    union { unsigned u; float f; } v;
    v.u = ((unsigned)(unsigned short)s) << 16;
    return v.f;
}
__device__ inline short f2b(float f) {
    unsigned u = __float_as_uint(f);
    unsigned r = (u + 0x7fffu + ((u >> 16) & 1u)) >> 16;
    return (short)r;
}

template <bool F32>
__device__ inline float ld1(const void* p, size_t i) {
    return F32 ? ((const float*)p)[i] : b2f(((const short*)p)[i]);
}

template <bool F32>
__device__ inline void load8(const void* p, size_t off, float v[8]) {
    if (F32) {
        const float4* q = (const float4*)((const float*)p + off);
        float4 a = q[0], b = q[1];
        v[0] = a.x; v[1] = a.y; v[2] = a.z; v[3] = a.w;
        v[4] = b.x; v[5] = b.y; v[6] = b.z; v[7] = b.w;
    } else {
        short8 s = *(const short8*)((const short*)p + off);
#pragma unroll
        for (int j = 0; j < 8; ++j) v[j] = b2f(s[j]);
    }
}

// ---------------------------------------------------------------------------
// dtype probe: fp32 N(0,1) words have exponent field in [117,137] ~100% of the
// time; bf16-pair words land in {248..255, 0..3}. flag=1 -> inputs are fp32.
// ---------------------------------------------------------------------------
__global__ void probe_kernel(const unsigned* __restrict__ x, int* __restrict__ flag) {
    __shared__ int cnt;
    if (threadIdx.x == 0) cnt = 0;
    __syncthreads();
    int local = 0;
    for (int i = threadIdx.x; i < 1024; i += 256) {
        unsigned e = (x[i] >> 23) & 0xFFu;
        if (e >= 117u && e <= 137u) local++;
    }
    atomicAdd(&cnt, local);
    __syncthreads();
    if (threadIdx.x == 0) *flag = (cnt >= 512) ? 1 : 0;
}

// ---------------------------------------------------------------------------
// RMSNorm -> canonical bf16 xn
// ---------------------------------------------------------------------------
template <bool F32>
__global__ __launch_bounds__(256) void rmsnorm_kernel(
    const void* __restrict__ x, const void* __restrict__ w,
    short* __restrict__ xn, const int* __restrict__ flag) {
    if ((*flag == 1) != F32) return;
    const int t = blockIdx.x, tid = threadIdx.x;
    float v[8];
    load8<F32>(x, (size_t)t * DMODEL + tid * 8, v);
    float ss = 0.f;
#pragma unroll
    for (int j = 0; j < 8; ++j) ss += v[j] * v[j];
#pragma unroll
    for (int o = 32; o > 0; o >>= 1) ss += __shfl_down(ss, o, 64);
    __shared__ float sred[4];
    if ((tid & 63) == 0) sred[tid >> 6] = ss;
    __syncthreads();
    float r = rsqrtf((sred[0] + sred[1] + sred[2] + sred[3]) * (1.f / DMODEL) + 1e-5f);
    float wv[8];
    load8<F32>(w, (size_t)tid * 8, wv);
    short8 o8;
#pragma unroll
    for (int j = 0; j < 8; ++j) o8[j] = f2b(v[j] * r * wv[j]);
    *(short8*)(xn + (size_t)t * DMODEL + tid * 8) = o8;
}

// ---------------------------------------------------------------------------
// GEMM C[M,N] = A[M,K](bf16) * B[N,K]^T; B is bf16 (async LDS) or fp32
// (load+convert). 128x128 tile, BK=32, m97 structure.
// ---------------------------------------------------------------------------
template <bool F32B, bool ADD_RES, bool F32OUT>
__global__ __launch_bounds__(256) void gemm_bt(
    const short* __restrict__ A, const void* __restrict__ Bp,
    const void* __restrict__ RESp, void* __restrict__ Cp,
    int M, int N, int K, const int* __restrict__ flag) {
    if ((*flag == 1) != F32B) return;
    __shared__ __align__(16) short As[128 * 32];
    __shared__ __align__(16) short Bs[128 * 32];

    const int tid  = threadIdx.x;
    const int wave = tid >> 6;
    const int lane = tid & 63;
    const int lr   = lane & 15;
    const int q    = lane >> 4;
    const int m0   = blockIdx.x * 128;
    const int n0   = blockIdx.y * 128;
    const int wm   = (wave >> 1) * 64;
    const int wn   = (wave & 1) * 64;

    f32x4 acc[4][4] = {};

    for (int k0 = 0; k0 < K; k0 += 32) {
#pragma unroll
        for (int p = 0; p < 2; ++p) {          // A staging: 512 x 16B chunks
            int i16 = p * 256 + tid;
            int row = i16 >> 2, ch = i16 & 3;
            const short* ga = A + (size_t)(m0 + row) * K + k0 + ch * 8;
            __builtin_amdgcn_global_load_lds(
                (const __attribute__((address_space(1))) void*)ga,
                (__attribute__((address_space(3))) void*)((char*)As + i16 * 16),
                16, 0, 0);
        }
        if (!F32B) {
#pragma unroll
            for (int p = 0; p < 2; ++p) {
                int i16 = p * 256 + tid;
                int row = i16 >> 2, ch = i16 & 3;
                const short* gb = (const short*)Bp + (size_t)(n0 + row) * K + k0 + ch * 8;
                __builtin_amdgcn_global_load_lds(
                    (const __attribute__((address_space(1))) void*)gb,
                    (__attribute__((address_space(3))) void*)((char*)Bs + i16 * 16),
                    16, 0, 0);
            }
        } else {
            int row = tid >> 1, half = tid & 1;
            const float4* gb = (const float4*)((const float*)Bp +
                               (size_t)(n0 + row) * K + k0 + half * 16);
            float4 f0 = gb[0], f1 = gb[1], f2 = gb[2], f3 = gb[3];
            short8 s0, s1;
            s0[0] = f2b(f0.x); s0[1] = f2b(f0.y); s0[2] = f2b(f0.z); s0[3] = f2b(f0.w);
            s0[4] = f2b(f1.x); s0[5] = f2b(f1.y); s0[6] = f2b(f1.z); s0[7] = f2b(f1.w);
            s1[0] = f2b(f2.x); s1[1] = f2b(f2.y); s1[2] = f2b(f2.z); s1[3] = f2b(f2.w);
            s1[4] = f2b(f3.x); s1[5] = f2b(f3.y); s1[6] = f2b(f3.z); s1[7] = f2b(f3.w);
            *(short8*)&Bs[row * 32 + half * 16]     = s0;
            *(short8*)&Bs[row * 32 + half * 16 + 8] = s1;
        }
        __syncthreads();

        short8 af[4], bfr[4];
#pragma unroll
        for (int i = 0; i < 4; ++i) {
            af[i]  = *(const short8*)&As[(wm + i * 16 + lr) * 32 + q * 8];
            bfr[i] = *(const short8*)&Bs[(wn + i * 16 + lr) * 32 + q * 8];
        }
#pragma unroll
        for (int i = 0; i < 4; ++i)
#pragma unroll
            for (int j = 0; j < 4; ++j)
                acc[i][j] = __builtin_amdgcn_mfma_f32_16x16x32_bf16(
                    af[i], bfr[j], acc[i][j], 0, 0, 0);
        __syncthreads();
    }

#pragma unroll
    for (int i = 0; i < 4; ++i)
#pragma unroll
        for (int j = 0; j < 4; ++j)
#pragma unroll
            for (int r = 0; r < 4; ++r) {
                int m = m0 + wm + i * 16 + q * 4 + r;
                int n = n0 + wn + j * 16 + lr;
                size_t idx = (size_t)m * N + n;
                float v = acc[i][j][r];
                if (ADD_RES) v += ld1<F32OUT>(RESp, idx);
                if (F32OUT) ((float*)Cp)[idx] = v;
                else        ((short*)Cp)[idx] = f2b(v);
            }
}

// ---------------------------------------------------------------------------
// depthwise causal conv(K=4) + bias + SiLU -> bf16 xc
// ---------------------------------------------------------------------------
template <bool F32>
__global__ __launch_bounds__(256) void conv_silu_kernel(
    const short* __restrict__ xz, const void* __restrict__ cw,
    const void* __restrict__ cb, short* __restrict__ xc,
    const int* __restrict__ flag) {
    if ((*flag == 1) != F32) return;
    const int t = blockIdx.x;
    const int b = t >> 11, l = t & 2047;
    for (int c = threadIdx.x; c < DINNER; c += 256) {
        float acc = ld1<F32>(cb, c);
#pragma unroll
        for (int k = 0; k < 4; ++k) {
            int ls = l - 3 + k;
            if (ls >= 0)
                acc += b2f(xz[(size_t)(b * LSEQ + ls) * (2 * DINNER) + c]) *
                       ld1<F32>(cw, c * 4 + k);
        }
        float s = acc / (1.f + __expf(-acc));
        xc[(size_t)t * DINNER + c] = f2b(s);
    }
}

// ---------------------------------------------------------------------------
// x_proj -> fp32 x_ssm (NTOK x 33)
// ---------------------------------------------------------------------------
template <bool F32>
__global__ __launch_bounds__(256) void xproj_kernel(
    const short* __restrict__ xc, const void* __restrict__ W,
    float* __restrict__ out, const int* __restrict__ flag) {
    if ((*flag == 1) != F32) return;
    const int t = blockIdx.x, tid = threadIdx.x;
    float xv[16];
    load8<false>(xc, (size_t)t * DINNER + tid * 16, xv);
    load8<false>(xc, (size_t)t * DINNER + tid * 16 + 8, xv + 8);
    float acc[33];
#pragma unroll
    for (int e = 0; e < 33; ++e) {
        float wv[16];
        load8<F32>(W, (size_t)e * DINNER + tid * 16, wv);
        load8<F32>(W, (size_t)e * DINNER + tid * 16 + 8, wv + 8);
        float s = 0.f;
#pragma unroll
        for (int j = 0; j < 16; ++j) s += xv[j] * wv[j];
        acc[e] = s;
    }
    __shared__ float red[4][33];
#pragma unroll
    for (int e = 0; e < 33; ++e) {
        float v = acc[e];
#pragma unroll
        for (int o = 32; o > 0; o >>= 1) v += __shfl_down(v, o, 64);
        if ((tid & 63) == 0) red[tid >> 6][e] = v;
    }
    __syncthreads();
    if (tid < 33)
        out[(size_t)t * 33 + tid] = red[0][tid] + red[1][tid] + red[2][tid] + red[3][tid];
}

// ---------------------------------------------------------------------------
// selective scan, in-place: xc (u in) is overwritten with gated y (bf16)
// ---------------------------------------------------------------------------
template <bool F32>
__global__ __launch_bounds__(64) void scan_kernel(
    const float* __restrict__ xssm, short* __restrict__ xc,
    const short* __restrict__ xz, const void* __restrict__ dt_w,
    const void* __restrict__ dt_b, const void* __restrict__ A_log,
    const void* __restrict__ D_par, const int* __restrict__ flag) {
    if ((*flag == 1) != F32) return;
    const int g = blockIdx.x * 64 + threadIdx.x;
    const int b = g >> 12;
    const int c = g & 4095;

    float A[NSTATE];
#pragma unroll
    for (int n = 0; n < NSTATE; ++n) A[n] = -__expf(ld1<F32>(A_log, c * NSTATE + n));
    const float dtw = ld1<F32>(dt_w, c);
    const float dtb = ld1<F32>(dt_b, c);
    const float Dp  = ld1<F32>(D_par, c);

    float h[NSTATE];
#pragma unroll
    for (int n = 0; n < NSTATE; ++n) h[n] = 0.f;

    for (int l = 0; l < LSEQ; ++l) {
        const size_t t = (size_t)b * LSEQ + l;
        const float* row = xssm + t * 33;
        float v = row[32] * dtw + dtb;
        float dt = (v > 20.f) ? v : __logf(1.f + __expf(v));
        float u = b2f(xc[t * DINNER + c]);
        float du = dt * u;
        float y = Dp * u;
#pragma unroll
        for (int n = 0; n < NSTATE; ++n) {
            float dA = __expf(dt * A[n]);
            h[n] = dA * h[n] + du * row[n];
            y += h[n] * row[16 + n];
        }
        float z = b2f(xz[t * (2 * DINNER) + DINNER + c]);
        float zg = z / (1.f + __expf(-z));
        xc[t * DINNER + c] = f2b(y * zg);
    }
}

// ---------------------------------------------------------------------------
extern "C" void kernel_launch(void* const* d_in, const int* in_sizes, int n_in,
                              void* d_out, int out_size, void* d_ws, size_t ws_size,
                              hipStream_t stream) {
    const void* x      = d_in[0];
    const void* norm_w = d_in[1];
    const void* w_in   = d_in[2];   // (8192, 2048)
    const void* conv_w = d_in[3];
    const void* conv_b = d_in[4];
    const void* w_xp   = d_in[5];   // (33, 4096)
    const void* dt_w   = d_in[6];
    const void* dt_b   = d_in[7];
    const void* A_log  = d_in[8];
    const void* D_par  = d_in[9];
    const void* w_out  = d_in[10];  // (2048, 4096)

    char* ws = (char*)d_ws;
    short* xn  = (short*)(ws);                          // 16 MB
    short* xz  = (short*)(ws + (size_t)(16 << 20));     // 64 MB
    short* xc  = (short*)(ws + (size_t)(80 << 20));     // 32 MB (y written in-place)
    float* xsm = (float*)(ws + (size_t)(112 << 20));    // 0.6 MB
    int*  flag = (int*)  (ws + (size_t)(113 << 20));

    probe_kernel<<<1, 256, 0, stream>>>((const unsigned*)x, flag);

    rmsnorm_kernel<false><<<NTOK, 256, 0, stream>>>(x, norm_w, xn, flag);
    rmsnorm_kernel<true ><<<NTOK, 256, 0, stream>>>(x, norm_w, xn, flag);

    dim3 g1(NTOK / 128, 8192 / 128);
    gemm_bt<false, false, false><<<g1, 256, 0, stream>>>(xn, w_in, nullptr, xz,
                                                         NTOK, 2 * DINNER, DMODEL, flag);
    gemm_bt<true, false, false><<<g1, 256, 0, stream>>>(xn, w_in, nullptr, xz,
                                                        NTOK, 2 * DINNER, DMODEL, flag);

    conv_silu_kernel<false><<<NTOK, 256, 0, stream>>>(xz, conv_w, conv_b, xc, flag);
    conv_silu_kernel<true ><<<NTOK, 256, 0, stream>>>(xz, conv_w, conv_b, xc, flag);

    xproj_kernel<false><<<NTOK, 256, 0, stream>>>(xc, w_xp, xsm, flag);
    xproj_kernel<true ><<<NTOK, 256, 0, stream>>>(xc, w_xp, xsm, flag);

    scan_kernel<false><<<8192 / 64, 64, 0, stream>>>(xsm, xc, xz, dt_w, dt_b,
                                                     A_log, D_par, flag);
    scan_kernel<true ><<<8192 / 64, 64, 0, stream>>>(xsm, xc, xz, dt_w, dt_b,
                                                     A_log, D_par, flag);

    dim3 g2(NTOK / 128, DMODEL / 128);
    gemm_bt<false, true, false><<<g2, 256, 0, stream>>>(xc, w_out, x, d_out,
                                                        NTOK, DMODEL, DINNER, flag);
    gemm_bt<true, true, true><<<g2, 256, 0, stream>>>(xc, w_out, x, d_out,
                                                      NTOK, DMODEL, DINNER, flag);
}

// Round 7
// 1609.790 us; speedup vs baseline: 1.4759x; 1.4759x over previous
//
#include <hip/hip_runtime.h>

#define NTOK   4096   // BATCH * L
#define LSEQ   2048
#define DMODEL 2048
#define DINNER 4096
#define NSTATE 16
#define NCHAIN 8192   // BATCH * DINNER

using short8 = __attribute__((ext_vector_type(8))) short;
using f32x4  = __attribute__((ext_vector_type(4))) float;

__device__ inline float b2f(short s) {
    union { unsigned u; float f; } v;
    v.u = ((unsigned)(unsigned short)s) << 16;
    return v.f;
}
__device__ inline short f2b(float f) {
    unsigned u = __float_as_uint(f);
    unsigned r = (u + 0x7fffu + ((u >> 16) & 1u)) >> 16;
    return (short)r;
}

// ---------------------------------------------------------------------------
// fp32 -> bf16 bulk convert (8 elems/thread)
// ---------------------------------------------------------------------------
__global__ __launch_bounds__(256) void f32_to_bf16_kernel(
    const float* __restrict__ in, short* __restrict__ out, int n8) {
    int i = blockIdx.x * 256 + threadIdx.x;
    if (i >= n8) return;
    const float4* p = (const float4*)in + 2 * (size_t)i;
    float4 a = p[0], b = p[1];
    short8 s;
    s[0] = f2b(a.x); s[1] = f2b(a.y); s[2] = f2b(a.z); s[3] = f2b(a.w);
    s[4] = f2b(b.x); s[5] = f2b(b.y); s[6] = f2b(b.z); s[7] = f2b(b.w);
    *(short8*)(out + 8 * (size_t)i) = s;
}

// ---------------------------------------------------------------------------
// RMSNorm: x (NTOK x DMODEL fp32) -> xn bf16
// ---------------------------------------------------------------------------
__global__ __launch_bounds__(256) void rmsnorm_kernel(
    const float* __restrict__ x, const float* __restrict__ w,
    short* __restrict__ xn) {
    const int t = blockIdx.x, tid = threadIdx.x;
    const float4* xr = (const float4*)(x + (size_t)t * DMODEL + tid * 8);
    float4 a = xr[0], b = xr[1];
    float v[8] = {a.x, a.y, a.z, a.w, b.x, b.y, b.z, b.w};
    float ss = 0.f;
#pragma unroll
    for (int j = 0; j < 8; ++j) ss += v[j] * v[j];
#pragma unroll
    for (int o = 32; o > 0; o >>= 1) ss += __shfl_down(ss, o, 64);
    __shared__ float sred[4];
    if ((tid & 63) == 0) sred[tid >> 6] = ss;
    __syncthreads();
    float r = rsqrtf((sred[0] + sred[1] + sred[2] + sred[3]) * (1.f / DMODEL) + 1e-5f);
    const float4* wr = (const float4*)(w + tid * 8);
    float4 wa = wr[0], wb = wr[1];
    float wv[8] = {wa.x, wa.y, wa.z, wa.w, wb.x, wb.y, wb.z, wb.w};
    short8 o8;
#pragma unroll
    for (int j = 0; j < 8; ++j) o8[j] = f2b(v[j] * r * wv[j]);
    *(short8*)(xn + (size_t)t * DMODEL + tid * 8) = o8;
}

// ---------------------------------------------------------------------------
// GEMM C[M,N] = A[M,K] * B[N,K]^T  (bf16 in, fp32 accum), m97 structure.
// Output bf16 or fp32(+fp32 residual).
// ---------------------------------------------------------------------------
template <bool ADD_RES, bool F32OUT>
__global__ __launch_bounds__(256) void gemm_bt(
    const short* __restrict__ A, const short* __restrict__ B,
    const float* __restrict__ RES, void* __restrict__ Cp,
    int M, int N, int K) {
    __shared__ __align__(16) short As[128 * 32];
    __shared__ __align__(16) short Bs[128 * 32];

    const int tid  = threadIdx.x;
    const int wave = tid >> 6;
    const int lane = tid & 63;
    const int lr   = lane & 15;
    const int q    = lane >> 4;
    const int m0   = blockIdx.x * 128;
    const int n0   = blockIdx.y * 128;
    const int wm   = (wave >> 1) * 64;
    const int wn   = (wave & 1) * 64;

    f32x4 acc[4][4] = {};

    for (int k0 = 0; k0 < K; k0 += 32) {
#pragma unroll
        for (int p = 0; p < 2; ++p) {
            int i16 = p * 256 + tid;
            int row = i16 >> 2, ch = i16 & 3;
            const short* ga = A + (size_t)(m0 + row) * K + k0 + ch * 8;
            const short* gb = B + (size_t)(n0 + row) * K + k0 + ch * 8;
            __builtin_amdgcn_global_load_lds(
                (const __attribute__((address_space(1))) void*)ga,
                (__attribute__((address_space(3))) void*)((char*)As + i16 * 16),
                16, 0, 0);
            __builtin_amdgcn_global_load_lds(
                (const __attribute__((address_space(1))) void*)gb,
                (__attribute__((address_space(3))) void*)((char*)Bs + i16 * 16),
                16, 0, 0);
        }
        __syncthreads();

        short8 af[4], bfr[4];
#pragma unroll
        for (int i = 0; i < 4; ++i) {
            af[i]  = *(const short8*)&As[(wm + i * 16 + lr) * 32 + q * 8];
            bfr[i] = *(const short8*)&Bs[(wn + i * 16 + lr) * 32 + q * 8];
        }
#pragma unroll
        for (int i = 0; i < 4; ++i)
#pragma unroll
            for (int j = 0; j < 4; ++j)
                acc[i][j] = __builtin_amdgcn_mfma_f32_16x16x32_bf16(
                    af[i], bfr[j], acc[i][j], 0, 0, 0);
        __syncthreads();
    }

#pragma unroll
    for (int i = 0; i < 4; ++i)
#pragma unroll
        for (int j = 0; j < 4; ++j)
#pragma unroll
            for (int r = 0; r < 4; ++r) {
                int m = m0 + wm + i * 16 + q * 4 + r;
                int n = n0 + wn + j * 16 + lr;
                size_t idx = (size_t)m * N + n;
                float v = acc[i][j][r];
                if (ADD_RES) v += RES[idx];
                if (F32OUT) ((float*)Cp)[idx] = v;
                else        ((short*)Cp)[idx] = f2b(v);
            }
}

// ---------------------------------------------------------------------------
// depthwise causal conv(K=4) + bias + SiLU -> bf16 xc  (weights fp32)
// ---------------------------------------------------------------------------
__global__ __launch_bounds__(256) void conv_silu_kernel(
    const short* __restrict__ xz, const float* __restrict__ cw,
    const float* __restrict__ cb, short* __restrict__ xc) {
    const int t = blockIdx.x;
    const int b = t >> 11, l = t & 2047;
    for (int c = threadIdx.x; c < DINNER; c += 256) {
        float acc = cb[c];
#pragma unroll
        for (int k = 0; k < 4; ++k) {
            int ls = l - 3 + k;
            if (ls >= 0)
                acc += b2f(xz[(size_t)(b * LSEQ + ls) * (2 * DINNER) + c]) *
                       cw[c * 4 + k];
        }
        xc[(size_t)t * DINNER + c] = f2b(acc / (1.f + __expf(-acc)));
    }
}

// ---------------------------------------------------------------------------
// x_proj -> fp32 x_ssm (NTOK x 33); xc bf16, W fp32
// ---------------------------------------------------------------------------
__global__ __launch_bounds__(256) void xproj_kernel(
    const short* __restrict__ xc, const float* __restrict__ W,
    float* __restrict__ out) {
    const int t = blockIdx.x, tid = threadIdx.x;
    float xv[16];
    {
        short8 a = *(const short8*)(xc + (size_t)t * DINNER + tid * 16);
        short8 b = *(const short8*)(xc + (size_t)t * DINNER + tid * 16 + 8);
#pragma unroll
        for (int j = 0; j < 8; ++j) { xv[j] = b2f(a[j]); xv[8 + j] = b2f(b[j]); }
    }
    float acc[33];
#pragma unroll
    for (int e = 0; e < 33; ++e) {
        const float4* wr = (const float4*)(W + (size_t)e * DINNER + tid * 16);
        float4 w0 = wr[0], w1 = wr[1], w2 = wr[2], w3 = wr[3];
        float wv[16] = {w0.x, w0.y, w0.z, w0.w, w1.x, w1.y, w1.z, w1.w,
                        w2.x, w2.y, w2.z, w2.w, w3.x, w3.y, w3.z, w3.w};
        float s = 0.f;
#pragma unroll
        for (int j = 0; j < 16; ++j) s += xv[j] * wv[j];
        acc[e] = s;
    }
    __shared__ float red[4][33];
#pragma unroll
    for (int e = 0; e < 33; ++e) {
        float v = acc[e];
#pragma unroll
        for (int o = 32; o > 0; o >>= 1) v += __shfl_down(v, o, 64);
        if ((tid & 63) == 0) red[tid >> 6][e] = v;
    }
    __syncthreads();
    if (tid < 33)
        out[(size_t)t * 33 + tid] = red[0][tid] + red[1][tid] + red[2][tid] + red[3][tid];
}

// ---------------------------------------------------------------------------
// State-parallel selective scan. One LANE per (chain, state); params fp32.
// Per step: 1 exp + shfl_xor(width=16) reduction; lane n==0 writes gated y.
// ---------------------------------------------------------------------------
__global__ __launch_bounds__(256) void scan_state_kernel(
    const float* __restrict__ xssm, short* __restrict__ xc,
    const short* __restrict__ xz, const float* __restrict__ dt_w,
    const float* __restrict__ dt_b, const float* __restrict__ A_log,
    const float* __restrict__ D_par) {
    const int tid   = threadIdx.x;
    const int n     = tid & 15;                        // state index
    const int chain = blockIdx.x * 16 + (tid >> 4);    // 16 chains per block
    const int b     = chain >> 12;                     // DINNER=4096
    const int c     = chain & (DINNER - 1);

    const float An  = -__expf(A_log[c * NSTATE + n]);
    const float dtw = dt_w[c];
    const float dtb = dt_b[c];
    const float Dp  = D_par[c];

    const float* rowb = xssm + (size_t)b * LSEQ * 33;
    const short* ub   = xc + (size_t)b * LSEQ * DINNER + c;
    const short* zb   = xz + (size_t)b * LSEQ * (2 * DINNER) + DINNER + c;

    float h = 0.f;

    float Bv = rowb[n], Cv = rowb[16 + n], s32 = rowb[32];
    float u = b2f(ub[0]);
    float z = b2f(zb[0]);

    for (int l = 0; l < LSEQ; ++l) {
        const int ln = (l + 1 < LSEQ) ? l + 1 : l;
        const float* rn = rowb + (size_t)ln * 33;
        float Bv2 = rn[n], Cv2 = rn[16 + n], s322 = rn[32];
        float u2 = b2f(ub[(size_t)ln * DINNER]);
        float z2 = b2f(zb[(size_t)ln * 2 * DINNER]);

        float v = s32 * dtw + dtb;
        float dt = (v > 20.f) ? v : __logf(1.f + __expf(v));
        h = __expf(dt * An) * h + (dt * u) * Bv;
        float part = h * Cv;
#pragma unroll
        for (int o = 8; o > 0; o >>= 1) part += __shfl_xor(part, o, 16);
        if (n == 0) {
            float y = part + Dp * u;
            float zg = z / (1.f + __expf(-z));
            xc[(size_t)(b * LSEQ + l) * DINNER + c] = f2b(y * zg);
        }
        Bv = Bv2; Cv = Cv2; s32 = s322; u = u2; z = z2;
    }
}

// ---------------------------------------------------------------------------
extern "C" void kernel_launch(void* const* d_in, const int* in_sizes, int n_in,
                              void* d_out, int out_size, void* d_ws, size_t ws_size,
                              hipStream_t stream) {
    const float* x      = (const float*)d_in[0];
    const float* norm_w = (const float*)d_in[1];
    const float* w_in   = (const float*)d_in[2];   // (8192, 2048)
    const float* conv_w = (const float*)d_in[3];
    const float* conv_b = (const float*)d_in[4];
    const float* w_xp   = (const float*)d_in[5];   // (33, 4096)
    const float* dt_w   = (const float*)d_in[6];
    const float* dt_b   = (const float*)d_in[7];
    const float* A_log  = (const float*)d_in[8];
    const float* D_par  = (const float*)d_in[9];
    const float* w_out  = (const float*)d_in[10];  // (2048, 4096)
    float* out = (float*)d_out;

    char* ws = (char*)d_ws;
    short* wb   = (short*)(ws);                        // 32 MB: w_in bf16, later w_out bf16
    short* xn   = (short*)(ws + (size_t)(32 << 20));   // 16 MB
    short* xz   = (short*)(ws + (size_t)(48 << 20));   // 64 MB
    short* xc   = (short*)(ws + (size_t)(112 << 20));  // 32 MB (y written in place)
    float* xsm  = (float*)(ws + (size_t)(144 << 20));  // 0.55 MB

    // 1. w_in -> bf16
    f32_to_bf16_kernel<<<(2 * DINNER * DMODEL / 8) / 256, 256, 0, stream>>>(
        w_in, wb, 2 * DINNER * DMODEL / 8);
    // 2. RMSNorm
    rmsnorm_kernel<<<NTOK, 256, 0, stream>>>(x, norm_w, xn);
    // 3. in_proj GEMM -> xz bf16
    gemm_bt<false, false><<<dim3(NTOK / 128, 8192 / 128), 256, 0, stream>>>(
        xn, wb, nullptr, xz, NTOK, 2 * DINNER, DMODEL);
    // 4. conv + SiLU -> xc bf16
    conv_silu_kernel<<<NTOK, 256, 0, stream>>>(xz, conv_w, conv_b, xc);
    // 5. x_proj -> xsm fp32
    xproj_kernel<<<NTOK, 256, 0, stream>>>(xc, w_xp, xsm);
    // 6. selective scan (in-place gated y into xc)
    scan_state_kernel<<<NCHAIN / 16, 256, 0, stream>>>(xsm, xc, xz, dt_w, dt_b,
                                                       A_log, D_par);
    // 7. w_out -> bf16 (reuse wb region; w_in copy dead after GEMM1)
    f32_to_bf16_kernel<<<(DMODEL * DINNER / 8) / 256, 256, 0, stream>>>(
        w_out, wb, DMODEL * DINNER / 8);
    // 8. out_proj GEMM + residual -> fp32 out
    gemm_bt<true, true><<<dim3(NTOK / 128, DMODEL / 128), 256, 0, stream>>>(
        xc, wb, x, out, NTOK, DMODEL, DINNER);
}